// Round 1
// baseline (1085.387 us; speedup 1.0000x reference)
//
#include <hip/hip_runtime.h>
#include <hip/hip_fp16.h>
#include <math.h>

// Problem: out = softmax(s @ X[:-1]^T) @ X[1:]
//   X: (8192, 1024) fp32,  s: (8191, 1024) fp32,  out: (8191, 1024) fp32
// Flash-attention structure, fp16 MFMA (16x16x32), fp32 accumulate.

#define NQ 8191
#define NK 8191
#define DD 1024
#define BQ 32
#define BK 128
#define KPAD 8192      // padded key count (Kh rows, Vt stride)
#define QS 1032        // Qs LDS stride in fp16 elems (mult of 8 -> 16B aligned rows)
#define SS 132         // Sbuf stride (f32)
#define PS 136         // Pbuf stride (fp16, mult of 8)
#define ITERS 64       // ceil(8191/128)

typedef _Float16 half8 __attribute__((ext_vector_type(8)));
typedef float float4v __attribute__((ext_vector_type(4)));

// ---------- prep: X -> Kh fp16 (row-major, rows 0..8190, row 8191 zeroed) ----------
__global__ void prep_k(const float* __restrict__ X, _Float16* __restrict__ Kh) {
    int idx = blockIdx.x * 256 + threadIdx.x;      // over 8192*1024
    int row = idx >> 10;
    float v = (row < NK) ? X[idx] : 0.f;
    Kh[idx] = (_Float16)v;
}

// ---------- prep: X[1:] -> Vt fp16 transposed: Vt[d][k] = X[k+1][d], k=8191 zeroed ----------
__global__ void prep_vt(const float* __restrict__ X, _Float16* __restrict__ Vt) {
    __shared__ float tile[64][65];
    int d0 = blockIdx.x * 64;     // 16 blocks over D
    int k0 = blockIdx.y * 64;     // 128 blocks over keys
    int tx = threadIdx.x;         // 0..63
    int ty = threadIdx.y;         // 0..3
    for (int i = 0; i < 16; ++i) {
        int k = k0 + ty * 16 + i;
        float v = (k < NK) ? X[(size_t)(k + 1) * DD + d0 + tx] : 0.f;
        tile[tx][ty * 16 + i] = v;               // tile[d_local][k_local]
    }
    __syncthreads();
    for (int i = 0; i < 16; ++i) {
        int dl = ty * 16 + i;
        Vt[(size_t)(d0 + dl) * KPAD + k0 + tx] = (_Float16)tile[dl][tx];
    }
}

// ---------- flash attention ----------
__launch_bounds__(512, 1)
__global__ void flash(const float* __restrict__ s,
                      const _Float16* __restrict__ Kh,
                      const _Float16* __restrict__ Vt,
                      float* __restrict__ out) {
    __shared__ _Float16 Qs[BQ][QS];
    __shared__ float    Sb[BQ][SS];
    __shared__ _Float16 Pb[BQ][PS];
    __shared__ float    mS[BQ], lS[BQ], aS[BQ];

    const int t  = threadIdx.x;
    const int w  = t >> 6;      // wave 0..7
    const int l  = t & 63;
    const int ln = l & 15;      // lane-low: n-index / m-index
    const int q4 = l >> 4;      // quad 0..3
    const int q0 = blockIdx.x * BQ;

    // stage Q tile (fp32 global -> fp16 LDS), zero-pad rows past NQ
    for (int e = t; e < BQ * DD; e += 512) {
        int r = e >> 10, d = e & (DD - 1);
        float v = (q0 + r < NQ) ? s[(size_t)(q0 + r) * DD + d] : 0.f;
        Qs[r][d] = (_Float16)v;
    }
    if (t < BQ) { mS[t] = -INFINITY; lS[t] = 0.f; }
    __syncthreads();

    // O accumulator: 32 rows x 128 cols per wave (wave w owns d in [w*128, w*128+128))
    float4v o[2][8];
    for (int b = 0; b < 2; ++b)
        for (int ct = 0; ct < 8; ++ct)
            o[b][ct] = (float4v){0.f, 0.f, 0.f, 0.f};

    for (int it = 0; it < ITERS; ++it) {
        const int kb = it * BK;

        // ---- phase 1: S = Q . K^T for this wave's 16 keys (full D contraction) ----
        float4v sa0 = (float4v){0.f, 0.f, 0.f, 0.f};
        float4v sa1 = (float4v){0.f, 0.f, 0.f, 0.f};
        const _Float16* kp  = Kh + (size_t)(kb + w * 16 + ln) * DD + q4 * 8;
        const _Float16* qp0 = &Qs[ln][q4 * 8];
        const _Float16* qp1 = &Qs[16 + ln][q4 * 8];
        #pragma unroll 8
        for (int kk = 0; kk < 32; ++kk) {
            half8 bf = *(const half8*)(kp  + kk * 32);
            half8 a0 = *(const half8*)(qp0 + kk * 32);
            half8 a1 = *(const half8*)(qp1 + kk * 32);
            sa0 = __builtin_amdgcn_mfma_f32_16x16x32_f16(a0, bf, sa0, 0, 0, 0);
            sa1 = __builtin_amdgcn_mfma_f32_16x16x32_f16(a1, bf, sa1, 0, 0, 0);
        }
        // write S tile: row = band*16 + q4*4 + r, col = w*16 + ln
        #pragma unroll
        for (int r = 0; r < 4; ++r) {
            Sb[q4 * 4 + r][w * 16 + ln]      = sa0[r];
            Sb[16 + q4 * 4 + r][w * 16 + ln] = sa1[r];
        }
        __syncthreads();

        // ---- phase 2: online softmax over the 128 new columns ----
        {
            const int row = t >> 4;       // 0..31
            const int sub = t & 15;       // 16 threads per row
            float sv[8];
            float tm = -INFINITY;
            #pragma unroll
            for (int j = 0; j < 8; ++j) {
                int c = sub * 8 + j;
                float v = (kb + c < NK) ? Sb[row][c] : -INFINITY;
                sv[j] = v;
                tm = fmaxf(tm, v);
            }
            #pragma unroll
            for (int m = 1; m < 16; m <<= 1) tm = fmaxf(tm, __shfl_xor(tm, m));
            float mo = mS[row];
            float mn = fmaxf(mo, tm);
            float ts = 0.f;
            #pragma unroll
            for (int j = 0; j < 8; ++j) {
                float p = __expf(sv[j] - mn);     // exp(-inf)=0 for masked cols
                ts += p;
                Pb[row][sub * 8 + j] = (_Float16)p;
            }
            #pragma unroll
            for (int m = 1; m < 16; m <<= 1) ts += __shfl_xor(ts, m);
            if (sub == 0) {
                float al = __expf(mo - mn);       // 0 on first iteration
                aS[row] = al;
                mS[row] = mn;
                lS[row] = lS[row] * al + ts;
            }
        }
        __syncthreads();

        // ---- phase 3: rescale O, then O += P . V_chunk ----
        float av0[4], av1[4];
        #pragma unroll
        for (int r = 0; r < 4; ++r) {
            av0[r] = aS[q4 * 4 + r];
            av1[r] = aS[16 + q4 * 4 + r];
        }
        #pragma unroll
        for (int ct = 0; ct < 8; ++ct)
            #pragma unroll
            for (int r = 0; r < 4; ++r) {
                o[0][ct][r] *= av0[r];
                o[1][ct][r] *= av1[r];
            }
        const int dcol = w * 128;
        #pragma unroll
        for (int kk = 0; kk < 4; ++kk) {
            half8 a0 = *(const half8*)(&Pb[ln][kk * 32 + q4 * 8]);
            half8 a1 = *(const half8*)(&Pb[16 + ln][kk * 32 + q4 * 8]);
            #pragma unroll
            for (int ct = 0; ct < 8; ++ct) {
                const _Float16* vp = Vt + (size_t)(dcol + ct * 16 + ln) * KPAD
                                     + kb + kk * 32 + q4 * 8;
                half8 bf = *(const half8*)vp;
                o[0][ct] = __builtin_amdgcn_mfma_f32_16x16x32_f16(a0, bf, o[0][ct], 0, 0, 0);
                o[1][ct] = __builtin_amdgcn_mfma_f32_16x16x32_f16(a1, bf, o[1][ct], 0, 0, 0);
            }
        }
        // next iteration's Sb writes are ordered by the next phase-1->phase-2 barrier
    }

    // ---- epilogue: normalize by l and store ----
    float li0[4], li1[4];
    #pragma unroll
    for (int r = 0; r < 4; ++r) {
        li0[r] = 1.f / lS[q4 * 4 + r];
        li1[r] = 1.f / lS[16 + q4 * 4 + r];
    }
    #pragma unroll
    for (int ct = 0; ct < 8; ++ct) {
        #pragma unroll
        for (int r = 0; r < 4; ++r) {
            int row0 = q0 + q4 * 4 + r;
            int row1 = row0 + 16;
            int col  = w * 128 + ct * 16 + ln;
            if (row0 < NQ) out[(size_t)row0 * DD + col] = o[0][ct][r] * li0[r];
            if (row1 < NQ) out[(size_t)row1 * DD + col] = o[1][ct][r] * li1[r];
        }
    }
}

extern "C" void kernel_launch(void* const* d_in, const int* in_sizes, int n_in,
                              void* d_out, int out_size, void* d_ws, size_t ws_size,
                              hipStream_t stream) {
    const float* X = (const float*)d_in[0];
    const float* s = (const float*)d_in[1];
    float* out = (float*)d_out;

    _Float16* Kh = (_Float16*)d_ws;                       // 8192*1024 fp16 = 16 MiB
    _Float16* Vt = Kh + (size_t)KPAD * DD;                // 1024*8192 fp16 = 16 MiB

    prep_k<<<(KPAD * DD) / 256, 256, 0, stream>>>(X, Kh);
    prep_vt<<<dim3(DD / 64, KPAD / 64), dim3(64, 4), 0, stream>>>(X, Vt);
    flash<<<(NQ + BQ - 1) / BQ, 512, 0, stream>>>(s, Kh, Vt, out);
}

// Round 2
// 1064.097 us; speedup vs baseline: 1.0200x; 1.0200x over previous
//
#include <hip/hip_runtime.h>
#include <hip/hip_fp16.h>
#include <math.h>

// out = softmax(s @ X[:-1]^T) @ X[1:]
//   X: (8192,1024) fp32, s: (8191,1024) fp32, out: (8191,1024) fp32
// Flash attention, fp16 MFMA 16x16x32, fp32 accum.
// R2: 1024-thread blocks (16 waves, 50% occupancy), BK=256, 32 iters.

#define NQ 8191
#define NK 8191
#define DD 1024
#define BQ 32
#define BK 256
#define KPAD 8192
#define QS 1032        // Qs stride (halfs): 2064B=516dw, bank 4r -> 2-way free
#define SS 260         // Sb stride (f32): 260dw%32=4
#define PS 264         // Pb stride (halfs): 528B=132dw%32=4
#define ITERS 32       // 8191/256 rounded up
#define NW 16          // waves per block
#define NT 1024

typedef _Float16 half8 __attribute__((ext_vector_type(8)));
typedef float float4v __attribute__((ext_vector_type(4)));

__global__ void prep_k(const float* __restrict__ X, _Float16* __restrict__ Kh) {
    int idx = blockIdx.x * 256 + threadIdx.x;
    int row = idx >> 10;
    float v = (row < NK) ? X[idx] : 0.f;
    Kh[idx] = (_Float16)v;
}

__global__ void prep_vt(const float* __restrict__ X, _Float16* __restrict__ Vt) {
    __shared__ float tile[64][65];
    int d0 = blockIdx.x * 64;
    int k0 = blockIdx.y * 64;
    int tx = threadIdx.x;
    int ty = threadIdx.y;
    for (int i = 0; i < 16; ++i) {
        int k = k0 + ty * 16 + i;
        float v = (k < NK) ? X[(size_t)(k + 1) * DD + d0 + tx] : 0.f;
        tile[tx][ty * 16 + i] = v;
    }
    __syncthreads();
    for (int i = 0; i < 16; ++i) {
        int dl = ty * 16 + i;
        Vt[(size_t)(d0 + dl) * KPAD + k0 + tx] = (_Float16)tile[dl][tx];
    }
}

__launch_bounds__(NT, 4)
__global__ void flash(const float* __restrict__ s,
                      const _Float16* __restrict__ Kh,
                      const _Float16* __restrict__ Vt,
                      float* __restrict__ out) {
    __shared__ _Float16 Qs[BQ][QS];
    __shared__ float    Sb[BQ][SS];
    __shared__ _Float16 Pb[BQ][PS];
    __shared__ float    mS[BQ], lS[BQ], aS[BQ];

    const int t  = threadIdx.x;
    const int w  = t >> 6;      // wave 0..15
    const int l  = t & 63;
    const int ln = l & 15;
    const int q4 = l >> 4;
    const int q0 = blockIdx.x * BQ;

    // stage Q tile fp32->fp16
    for (int e = t; e < BQ * DD; e += NT) {
        int r = e >> 10, d = e & (DD - 1);
        float v = (q0 + r < NQ) ? s[(size_t)(q0 + r) * DD + d] : 0.f;
        Qs[r][d] = (_Float16)v;
    }
    if (t < BQ) { mS[t] = -INFINITY; lS[t] = 0.f; }
    __syncthreads();

    // O accumulator: wave w owns D chunk [w*64, w*64+64): 2 bands x 4 col-tiles
    float4v o[2][4];
    for (int b = 0; b < 2; ++b)
        for (int ct = 0; ct < 4; ++ct)
            o[b][ct] = (float4v){0.f, 0.f, 0.f, 0.f};

    for (int it = 0; it < ITERS; ++it) {
        const int kb = it * BK;

        // ---- phase 1: S for this wave's 16 keys, full-D contraction ----
        float4v sa0 = (float4v){0.f, 0.f, 0.f, 0.f};
        float4v sa1 = (float4v){0.f, 0.f, 0.f, 0.f};
        const _Float16* kp  = Kh + (size_t)(kb + w * 16 + ln) * DD + q4 * 8;
        const _Float16* qp0 = &Qs[ln][q4 * 8];
        const _Float16* qp1 = &Qs[16 + ln][q4 * 8];
        #pragma unroll 8
        for (int kk = 0; kk < 32; ++kk) {
            half8 bf = *(const half8*)(kp  + kk * 32);
            half8 a0 = *(const half8*)(qp0 + kk * 32);
            half8 a1 = *(const half8*)(qp1 + kk * 32);
            sa0 = __builtin_amdgcn_mfma_f32_16x16x32_f16(a0, bf, sa0, 0, 0, 0);
            sa1 = __builtin_amdgcn_mfma_f32_16x16x32_f16(a1, bf, sa1, 0, 0, 0);
        }
        #pragma unroll
        for (int r = 0; r < 4; ++r) {
            Sb[q4 * 4 + r][w * 16 + ln]      = sa0[r];
            Sb[16 + q4 * 4 + r][w * 16 + ln] = sa1[r];
        }
        __syncthreads();

        // ---- phase 2: online softmax over 256 new columns ----
        {
            const int row = t >> 5;       // 0..31
            const int sub = t & 31;       // 32 threads per row, 8 cols each
            float sv[8];
            float tm = -INFINITY;
            #pragma unroll
            for (int j = 0; j < 8; ++j) {
                int c = sub * 8 + j;
                float v = (kb + c < NK) ? Sb[row][c] : -INFINITY;
                sv[j] = v;
                tm = fmaxf(tm, v);
            }
            #pragma unroll
            for (int m = 1; m < 32; m <<= 1) tm = fmaxf(tm, __shfl_xor(tm, m, 32));
            float mo = mS[row];
            float mn = fmaxf(mo, tm);
            float ts = 0.f;
            #pragma unroll
            for (int j = 0; j < 8; ++j) {
                float p = __expf(sv[j] - mn);
                ts += p;
                Pb[row][sub * 8 + j] = (_Float16)p;
            }
            #pragma unroll
            for (int m = 1; m < 32; m <<= 1) ts += __shfl_xor(ts, m, 32);
            if (sub == 0) {
                float al = __expf(mo - mn);
                aS[row] = al;
                mS[row] = mn;
                lS[row] = lS[row] * al + ts;
            }
        }
        __syncthreads();

        // ---- phase 3: rescale O, O += P . V_chunk (64-wide D per wave) ----
        float av0[4], av1[4];
        #pragma unroll
        for (int r = 0; r < 4; ++r) {
            av0[r] = aS[q4 * 4 + r];
            av1[r] = aS[16 + q4 * 4 + r];
        }
        #pragma unroll
        for (int ct = 0; ct < 4; ++ct)
            #pragma unroll
            for (int r = 0; r < 4; ++r) {
                o[0][ct][r] *= av0[r];
                o[1][ct][r] *= av1[r];
            }
        const int dcol = w * 64;
        #pragma unroll
        for (int kk = 0; kk < 8; ++kk) {
            half8 a0 = *(const half8*)(&Pb[ln][kk * 32 + q4 * 8]);
            half8 a1 = *(const half8*)(&Pb[16 + ln][kk * 32 + q4 * 8]);
            #pragma unroll
            for (int ct = 0; ct < 4; ++ct) {
                const _Float16* vp = Vt + (size_t)(dcol + ct * 16 + ln) * KPAD
                                     + kb + kk * 32 + q4 * 8;
                half8 bf = *(const half8*)vp;
                o[0][ct] = __builtin_amdgcn_mfma_f32_16x16x32_f16(a0, bf, o[0][ct], 0, 0, 0);
                o[1][ct] = __builtin_amdgcn_mfma_f32_16x16x32_f16(a1, bf, o[1][ct], 0, 0, 0);
            }
        }
    }

    // ---- epilogue ----
    float li0[4], li1[4];
    #pragma unroll
    for (int r = 0; r < 4; ++r) {
        li0[r] = 1.f / lS[q4 * 4 + r];
        li1[r] = 1.f / lS[16 + q4 * 4 + r];
    }
    #pragma unroll
    for (int ct = 0; ct < 4; ++ct) {
        #pragma unroll
        for (int r = 0; r < 4; ++r) {
            int row0 = q0 + q4 * 4 + r;
            int row1 = row0 + 16;
            int col  = w * 64 + ct * 16 + ln;
            if (row0 < NQ) out[(size_t)row0 * DD + col] = o[0][ct][r] * li0[r];
            if (row1 < NQ) out[(size_t)row1 * DD + col] = o[1][ct][r] * li1[r];
        }
    }
}

extern "C" void kernel_launch(void* const* d_in, const int* in_sizes, int n_in,
                              void* d_out, int out_size, void* d_ws, size_t ws_size,
                              hipStream_t stream) {
    const float* X = (const float*)d_in[0];
    const float* s = (const float*)d_in[1];
    float* out = (float*)d_out;

    _Float16* Kh = (_Float16*)d_ws;                 // 16 MiB
    _Float16* Vt = Kh + (size_t)KPAD * DD;          // 16 MiB

    prep_k<<<(KPAD * DD) / 256, 256, 0, stream>>>(X, Kh);
    prep_vt<<<dim3(DD / 64, KPAD / 64), dim3(64, 4), 0, stream>>>(X, Vt);
    flash<<<(NQ + BQ - 1) / BQ, NT, 0, stream>>>(s, Kh, Vt, out);
}